// Round 3
// baseline (178.958 us; speedup 1.0000x reference)
//
#include <hip/hip_runtime.h>

// PointNet++ set abstraction: ball query (first-16-by-index within r=0.5) +
// gather + rel-coords/feat concat + 2-layer MLP (leaky 0.1) + max-pool.
// B=4, N=16384, M=4096, K=16.
//
// Round 2: latency/imbalance attack.
//  - Pre-pass packs {x,y,z,|p|^2} and {fx,fy,fz,0} as float4 in ws
//    (sq computed with the exact rn mul/add sequence of the reference).
//  - Scan processes 256 points/iter (4 x float4 independent loads per lane).
//  - Queries are processed in descending |q|^2 order (32-bucket counting
//    sort) so the ~9% full-scan stragglers dispatch first and co-schedule.
//  - d2 boundary semantics identical to the round-1 PASS kernel.

constexpr int N_PTS = 16384;
constexpr int M_Q   = 4096;
constexpr int KNN   = 16;
constexpr int TOTAL_Q = 4 * M_Q;     // 16384
constexpr int TOTAL_P = 4 * N_PTS;   // 65536

// ---- ws layout ----
constexpr size_t WS_PKX   = 0;                         // float4[65536]
constexpr size_t WS_PKF   = WS_PKX + (size_t)TOTAL_P * 16;
constexpr size_t WS_PERM  = WS_PKF + (size_t)TOTAL_P * 16;   // int[16384]
constexpr size_t WS_KEYS  = WS_PERM + (size_t)TOTAL_Q * 4;   // int[16384]
constexpr size_t WS_HIST  = WS_KEYS + (size_t)TOTAL_Q * 4;   // int[32]
constexpr size_t WS_CURS  = WS_HIST + 128;                   // int[32]
constexpr size_t WS_NEED  = WS_CURS + 128;

// ---------------- pre-pass A: pack points ----------------
__global__ __launch_bounds__(256) void pack_kernel(
    const float* __restrict__ xyz, const float* __restrict__ feat,
    float4* __restrict__ pkX, float4* __restrict__ pkF)
{
    const int i = blockIdx.x * 256 + threadIdx.x;
    if (i >= TOTAL_P) return;
    const float x = xyz[i * 3 + 0], y = xyz[i * 3 + 1], z = xyz[i * 3 + 2];
    // EXACT same expression as reference sum(p**2): rn mul/add, left-assoc.
    const float sq = __fadd_rn(__fadd_rn(__fmul_rn(x, x), __fmul_rn(y, y)),
                               __fmul_rn(z, z));
    pkX[i] = make_float4(x, y, z, sq);
    pkF[i] = make_float4(feat[i * 3 + 0], feat[i * 3 + 1], feat[i * 3 + 2], 0.0f);
}

// ---------------- pre-pass B: key + histogram ----------------
__global__ __launch_bounds__(256) void key_kernel(
    const int* __restrict__ fps, const float4* __restrict__ pkX,
    int* __restrict__ keys, int* __restrict__ hist)
{
    const int q = blockIdx.x * 256 + threadIdx.x;
    if (q >= TOTAL_Q) return;
    const int b = q >> 12;
    const int pidx = fps[q];
    const float sq = pkX[b * N_PTS + pidx].w;
    int key = (int)(2.0f * sq);
    key = key < 0 ? 0 : (key > 31 ? 31 : key);
    keys[q] = key;
    atomicAdd(&hist[key], 1);
}

// ---------------- pre-pass C: descending exclusive prefix ----------------
__global__ void prefix_kernel(const int* __restrict__ hist, int* __restrict__ curs)
{
    if (threadIdx.x == 0) {
        int run = 0;
        for (int k = 31; k >= 0; --k) { curs[k] = run; run += hist[k]; }
    }
}

// ---------------- pre-pass D: scatter permutation ----------------
__global__ __launch_bounds__(256) void scatter_kernel(
    const int* __restrict__ keys, int* __restrict__ curs, int* __restrict__ perm)
{
    const int q = blockIdx.x * 256 + threadIdx.x;
    if (q >= TOTAL_Q) return;
    const int pos = atomicAdd(&curs[keys[q]], 1);
    perm[pos] = q;
}

// ---------------- main fused kernel ----------------
__global__ __launch_bounds__(256) void pe_flow_fused2_kernel(
    const float4* __restrict__ pkX, const float4* __restrict__ pkF,
    const int*   __restrict__ fps, const int* __restrict__ perm,
    const float* __restrict__ W1, const float* __restrict__ b1,
    const float* __restrict__ W2, const float* __restrict__ b2,
    float* __restrict__ out)
{
    __shared__ float sW1[192];
    __shared__ float sW2[1024];
    __shared__ float sb1[32];
    __shared__ float sb2[32];
    __shared__ int   sNbr[4][KNN];

    const int tid = threadIdx.x;
    if (tid < 192) sW1[tid] = W1[tid];
    for (int i = tid; i < 1024; i += 256) sW2[i] = W2[i];
    if (tid < 32) { sb1[tid] = b1[tid]; sb2[tid] = b2[tid]; }
    __syncthreads();

    const int wave = tid >> 6;
    const int lane = tid & 63;
    const int w = blockIdx.x * 4 + wave;
    const int q = perm[w];                  // query id, 0..16383
    const int b = q >> 12;

    const float4* pX = pkX + (size_t)b * N_PTS;
    const float4* pF = pkF + (size_t)b * N_PTS;

    const int pidx = fps[q];
    const float4 Q = pX[pidx];
    const float qx = Q.x, qy = Q.y, qz = Q.z, sqq = Q.w;

    // ---- ball query: first 16 in-radius indices, ascending ----
    int count = 0;
    const unsigned long long lt_mask = (1ull << lane) - 1ull;
    for (int base = 0; base < N_PTS; base += 256) {
        float4 p[4];
        #pragma unroll
        for (int j = 0; j < 4; ++j) p[j] = pX[base + j * 64 + lane];
        #pragma unroll
        for (int j = 0; j < 4; ++j) {
            // dot as ascending FMA chain; d2 = (sqq + sqp) - 2*dot. Exact.
            float dot = __fmul_rn(qx, p[j].x);
            dot = __builtin_fmaf(qy, p[j].y, dot);
            dot = __builtin_fmaf(qz, p[j].z, dot);
            const float d2 = __fsub_rn(__fadd_rn(sqq, p[j].w), __fmul_rn(2.0f, dot));
            const bool hit = (d2 <= 0.25f);
            const unsigned long long mk = __ballot(hit);
            if (hit) {
                const int pos = count + __popcll(mk & lt_mask);
                if (pos < KNN) sNbr[wave][pos] = base + j * 64 + lane;
            }
            count += (int)__popcll(mk);
        }
        if (count >= KNN) break;   // wave-uniform
    }
    if (count < KNN) {
        const int first = sNbr[wave][0];   // count >= 1 (query point itself)
        if (lane >= count && lane < KNN) sNbr[wave][lane] = first;
    }

    // ---- fused MLP: 64 lanes = 16 neighbors x 4 channel-groups(8) ----
    const int k = lane >> 2;
    const int co = (lane & 3) * 8;
    const int ni = sNbr[wave][k];

    const float4 gx = pX[ni];
    const float4 gf = pF[ni];
    const float in0 = gx.x - qx;
    const float in1 = gx.y - qy;
    const float in2 = gx.z - qz;

    float h1[8];
    #pragma unroll
    for (int i = 0; i < 8; ++i) {
        float a = sb1[co + i];
        a += in0  * sW1[0 * 32 + co + i];
        a += in1  * sW1[1 * 32 + co + i];
        a += in2  * sW1[2 * 32 + co + i];
        a += gf.x * sW1[3 * 32 + co + i];
        a += gf.y * sW1[4 * 32 + co + i];
        a += gf.z * sW1[5 * 32 + co + i];
        h1[i] = (a >= 0.0f) ? a : 0.1f * a;
    }

    float h2[8];
    #pragma unroll
    for (int i = 0; i < 8; ++i) h2[i] = sb2[co + i];
    const int baseLane = lane & ~3;
    #pragma unroll
    for (int jj = 0; jj < 8; ++jj) {
        #pragma unroll
        for (int g = 0; g < 4; ++g) {
            const float v = __shfl(h1[jj], baseLane + g, 64);
            const int row = g * 8 + jj;
            #pragma unroll
            for (int i = 0; i < 8; ++i)
                h2[i] += v * sW2[row * 32 + co + i];
        }
    }

    #pragma unroll
    for (int i = 0; i < 8; ++i) {
        float v = h2[i];
        v = (v >= 0.0f) ? v : 0.1f * v;
        v = fmaxf(v, __shfl_xor(v, 4, 64));
        v = fmaxf(v, __shfl_xor(v, 8, 64));
        v = fmaxf(v, __shfl_xor(v, 16, 64));
        v = fmaxf(v, __shfl_xor(v, 32, 64));
        h2[i] = v;
    }

    if (k == 0) {
        float* op = out + (size_t)q * 32 + co;
        #pragma unroll
        for (int i = 0; i < 8; ++i) op[i] = h2[i];
    }
}

// ---------------- round-1 fallback (self-contained, proven PASS) ----------------
__global__ __launch_bounds__(256) void pe_flow_fused_kernel(
    const float* __restrict__ xyz, const float* __restrict__ feat,
    const int* __restrict__ fps,
    const float* __restrict__ W1, const float* __restrict__ b1,
    const float* __restrict__ W2, const float* __restrict__ b2,
    float* __restrict__ out)
{
    __shared__ float sW1[192];
    __shared__ float sW2[1024];
    __shared__ float sb1[32];
    __shared__ float sb2[32];
    __shared__ int   sNbr[4][KNN];

    const int tid = threadIdx.x;
    if (tid < 192) sW1[tid] = W1[tid];
    for (int i = tid; i < 1024; i += 256) sW2[i] = W2[i];
    if (tid < 32) { sb1[tid] = b1[tid]; sb2[tid] = b2[tid]; }
    __syncthreads();

    const int wave = tid >> 6;
    const int lane = tid & 63;
    const int q = blockIdx.x * 4 + wave;
    const int b = q >> 12;
    const int m = q & (M_Q - 1);

    const float* xb = xyz  + (size_t)b * N_PTS * 3;
    const float* fb = feat + (size_t)b * N_PTS * 3;

    const int pidx = fps[b * M_Q + m];
    const float qx = xb[pidx * 3 + 0];
    const float qy = xb[pidx * 3 + 1];
    const float qz = xb[pidx * 3 + 2];
    const float sq_q = __fadd_rn(__fadd_rn(__fmul_rn(qx, qx), __fmul_rn(qy, qy)),
                                 __fmul_rn(qz, qz));

    int count = 0;
    const unsigned long long lt_mask = (1ull << lane) - 1ull;
    for (int base = 0; base < N_PTS; base += 64) {
        const int i = base + lane;
        const float px = xb[i * 3 + 0];
        const float py = xb[i * 3 + 1];
        const float pz = xb[i * 3 + 2];
        const float sq_p = __fadd_rn(__fadd_rn(__fmul_rn(px, px), __fmul_rn(py, py)),
                                     __fmul_rn(pz, pz));
        float dot = __fmul_rn(qx, px);
        dot = __builtin_fmaf(qy, py, dot);
        dot = __builtin_fmaf(qz, pz, dot);
        const float d2 = __fsub_rn(__fadd_rn(sq_q, sq_p), __fmul_rn(2.0f, dot));
        const bool hit = (d2 <= 0.25f);
        const unsigned long long mk = __ballot(hit);
        if (hit) {
            const int pos = count + __popcll(mk & lt_mask);
            if (pos < KNN) sNbr[wave][pos] = i;
        }
        count += (int)__popcll(mk);
        if (count >= KNN) break;
    }
    if (count < KNN) {
        const int first = sNbr[wave][0];
        if (lane >= count && lane < KNN) sNbr[wave][lane] = first;
    }

    const int k = lane >> 2;
    const int co = (lane & 3) * 8;
    const int ni = sNbr[wave][k];

    const float in0 = xb[ni * 3 + 0] - qx;
    const float in1 = xb[ni * 3 + 1] - qy;
    const float in2 = xb[ni * 3 + 2] - qz;
    const float in3 = fb[ni * 3 + 0];
    const float in4 = fb[ni * 3 + 1];
    const float in5 = fb[ni * 3 + 2];

    float h1[8];
    #pragma unroll
    for (int i = 0; i < 8; ++i) {
        float a = sb1[co + i];
        a += in0 * sW1[0 * 32 + co + i];
        a += in1 * sW1[1 * 32 + co + i];
        a += in2 * sW1[2 * 32 + co + i];
        a += in3 * sW1[3 * 32 + co + i];
        a += in4 * sW1[4 * 32 + co + i];
        a += in5 * sW1[5 * 32 + co + i];
        h1[i] = (a >= 0.0f) ? a : 0.1f * a;
    }

    float h2[8];
    #pragma unroll
    for (int i = 0; i < 8; ++i) h2[i] = sb2[co + i];
    const int baseLane = lane & ~3;
    #pragma unroll
    for (int jj = 0; jj < 8; ++jj) {
        #pragma unroll
        for (int g = 0; g < 4; ++g) {
            const float v = __shfl(h1[jj], baseLane + g, 64);
            const int row = g * 8 + jj;
            #pragma unroll
            for (int i = 0; i < 8; ++i)
                h2[i] += v * sW2[row * 32 + co + i];
        }
    }

    #pragma unroll
    for (int i = 0; i < 8; ++i) {
        float v = h2[i];
        v = (v >= 0.0f) ? v : 0.1f * v;
        v = fmaxf(v, __shfl_xor(v, 4, 64));
        v = fmaxf(v, __shfl_xor(v, 8, 64));
        v = fmaxf(v, __shfl_xor(v, 16, 64));
        v = fmaxf(v, __shfl_xor(v, 32, 64));
        h2[i] = v;
    }

    if (k == 0) {
        float* op = out + (size_t)q * 32 + co;
        #pragma unroll
        for (int i = 0; i < 8; ++i) op[i] = h2[i];
    }
}

extern "C" void kernel_launch(void* const* d_in, const int* in_sizes, int n_in,
                              void* d_out, int out_size, void* d_ws, size_t ws_size,
                              hipStream_t stream) {
    const float* xyz  = (const float*)d_in[0];
    const float* feat = (const float*)d_in[1];
    const int*   fps  = (const int*)d_in[2];
    const float* W1   = (const float*)d_in[3];
    const float* b1   = (const float*)d_in[4];
    const float* W2   = (const float*)d_in[5];
    const float* b2   = (const float*)d_in[6];
    float* out = (float*)d_out;

    if (ws_size < WS_NEED) {
        // fallback: proven round-1 kernel, no workspace needed
        pe_flow_fused_kernel<<<TOTAL_Q / 4, 256, 0, stream>>>(
            xyz, feat, fps, W1, b1, W2, b2, out);
        return;
    }

    char* ws = (char*)d_ws;
    float4* pkX = (float4*)(ws + WS_PKX);
    float4* pkF = (float4*)(ws + WS_PKF);
    int* perm = (int*)(ws + WS_PERM);
    int* keys = (int*)(ws + WS_KEYS);
    int* hist = (int*)(ws + WS_HIST);
    int* curs = (int*)(ws + WS_CURS);

    hipMemsetAsync(hist, 0, 128, stream);
    pack_kernel<<<TOTAL_P / 256, 256, 0, stream>>>(xyz, feat, pkX, pkF);
    key_kernel<<<TOTAL_Q / 256, 256, 0, stream>>>(fps, pkX, keys, hist);
    prefix_kernel<<<1, 64, 0, stream>>>(hist, curs);
    scatter_kernel<<<TOTAL_Q / 256, 256, 0, stream>>>(keys, curs, perm);
    pe_flow_fused2_kernel<<<TOTAL_Q / 4, 256, 0, stream>>>(
        pkX, pkF, fps, perm, W1, b1, W2, b2, out);
}